// Round 1
// baseline (805.966 us; speedup 1.0000x reference)
//
#include <hip/hip_runtime.h>
#include <hip/hip_bf16.h>
#include <math.h>

// Problem constants (from reference): x[65536,2048] f32, W[64,2048] f32.
// Outputs flat-concatenated into d_out (float32): top2 idx (2N), top2 weights (2N), probs (64N).
constexpr int IN_DIM_C = 2048;
constexpr int NEXP     = 64;
constexpr int MTILE    = 128;  // tokens per block
constexpr int KC       = 64;   // K-chunk
constexpr int APAD     = 132;  // A_T row stride (128 tokens + 4): store bank pattern 2-way, 16B-aligned rows
constexpr int BPAD     = 68;   // B_T row stride (64 experts + 4)
constexpr int A_ELEMS  = KC * APAD;  // 8448 floats
constexpr int B_ELEMS  = KC * BPAD;  // 4352 floats

__global__ __launch_bounds__(256, 2)
void router_fused(const float* __restrict__ x, const float* __restrict__ W,
                  float* __restrict__ out_idx, float* __restrict__ out_w,
                  float* __restrict__ out_p) {
  __shared__ float smem[A_ELEMS + B_ELEMS];  // 51.2 KB -> 2-3 blocks/CU
  float* At = smem;             // At[k][tok], stride APAD
  float* Bt = smem + A_ELEMS;   // Bt[k][e],   stride BPAD

  const int tid = threadIdx.x;
  const int m0  = blockIdx.x * MTILE;

  // Compute-thread layout: 16 token-groups x 16 expert-groups.
  // Thread owns tokens {4tm..4tm+3} U {64+4tm..}, experts {4tn..4tn+3}.
  const int tm = tid & 15;
  const int tn = tid >> 4;

  float acc[8][4];
#pragma unroll
  for (int i = 0; i < 8; ++i)
#pragma unroll
    for (int j = 0; j < 4; ++j) acc[i][j] = 0.f;

  // Staging maps (chosen for coalesced global float4 loads + 2-way-max LDS store conflicts)
  const int a_tok  = tid >> 1;  // 0..127
  const int a_half = tid & 1;   // which 32-float half of the 64-k chunk
  const int b_e    = tid & 63;  // expert row
  const int b_kq   = tid >> 6;  // 16-k quarter

  const float* xrow = x + (size_t)(m0 + a_tok) * IN_DIM_C + a_half * 32;
  const float* wrow = W + (size_t)b_e * IN_DIM_C + b_kq * 16;

  for (int k0 = 0; k0 < IN_DIM_C; k0 += KC) {
    // Issue global loads before the barrier so latency overlaps the sync.
    float4 av[8];
#pragma unroll
    for (int i = 0; i < 8; ++i) av[i] = *(const float4*)(xrow + k0 + 4 * i);
    float4 bv[4];
#pragma unroll
    for (int i = 0; i < 4; ++i) bv[i] = *(const float4*)(wrow + k0 + 4 * i);

    __syncthreads();  // previous chunk's readers done

#pragma unroll
    for (int i = 0; i < 8; ++i) {
      const int kk = a_half * 32 + 4 * i;
      At[(kk + 0) * APAD + a_tok] = av[i].x;
      At[(kk + 1) * APAD + a_tok] = av[i].y;
      At[(kk + 2) * APAD + a_tok] = av[i].z;
      At[(kk + 3) * APAD + a_tok] = av[i].w;
    }
#pragma unroll
    for (int i = 0; i < 4; ++i) {
      const int kk = b_kq * 16 + 4 * i;
      Bt[(kk + 0) * BPAD + b_e] = bv[i].x;
      Bt[(kk + 1) * BPAD + b_e] = bv[i].y;
      Bt[(kk + 2) * BPAD + b_e] = bv[i].z;
      Bt[(kk + 3) * BPAD + b_e] = bv[i].w;
    }
    __syncthreads();

#pragma unroll 8
    for (int k = 0; k < KC; ++k) {
      const float4 a0 = *(const float4*)&At[k * APAD + 4 * tm];
      const float4 a1 = *(const float4*)&At[k * APAD + 64 + 4 * tm];
      const float4 b  = *(const float4*)&Bt[k * BPAD + 4 * tn];
      const float aa[8] = {a0.x, a0.y, a0.z, a0.w, a1.x, a1.y, a1.z, a1.w};
      const float bb[4] = {b.x, b.y, b.z, b.w};
#pragma unroll
      for (int i = 0; i < 8; ++i)
#pragma unroll
        for (int j = 0; j < 4; ++j)
          acc[i][j] = fmaf(aa[i], bb[j], acc[i][j]);
    }
  }

  __syncthreads();  // done with At/Bt; reuse smem for logits

  // Logits tile in LDS: L[tok][e], stride 65 (odd -> conflict-free row scans)
  float* L  = smem;             // 128*65 = 8320 floats
  float* Sv = smem + 128 * 65;  // per-token 1/sum

#pragma unroll
  for (int i = 0; i < 8; ++i) {
    const int tok = (i < 4) ? (4 * tm + i) : (60 + 4 * tm + i);  // 64 + 4tm + (i-4)
#pragma unroll
    for (int j = 0; j < 4; ++j) L[tok * 65 + 4 * tn + j] = acc[i][j];
  }
  __syncthreads();

  if (tid < MTILE) {
    const int tok = tid;
    // Top-2 on raw logits (exact ordering; ties keep lower index, matching lax.top_k)
    float v1 = -1e30f, v2 = -1e30f;
    int i1 = 0, i2 = 0;
    for (int e = 0; e < NEXP; ++e) {
      const float l = L[tok * 65 + e];
      if (l > v1) { v2 = v1; i2 = i1; v1 = l; i1 = e; }
      else if (l > v2) { v2 = l; i2 = e; }
    }
    // Softmax denominator (max = v1), overwrite row with unnormalized exps
    float S = 0.f;
    for (int e = 0; e < NEXP; ++e) {
      const float ex = __expf(L[tok * 65 + e] - v1);
      L[tok * 65 + e] = ex;
      S += ex;
    }
    Sv[tok] = 1.f / S;

    const float e2  = __expf(v2 - v1);
    const float inv = 1.f / (1.f + e2);
    const size_t g = (size_t)(m0 + tok);
    out_idx[g * 2 + 0] = (float)i1;   // indices as float values (d_out is float32)
    out_idx[g * 2 + 1] = (float)i2;
    out_w[g * 2 + 0]   = inv;         // = p1/(p1+p2)
    out_w[g * 2 + 1]   = e2 * inv;    // = p2/(p1+p2)
  }
  __syncthreads();

  // Cooperative, fully-coalesced probs write: one LDS row per wave (broadcast Sv)
  const size_t pbase = (size_t)m0 * NEXP;
#pragma unroll
  for (int r = 0; r < (MTILE * NEXP) / 256; ++r) {
    const int idx = r * 256 + tid;
    const int tok = idx >> 6, e = idx & 63;
    out_p[pbase + idx] = L[tok * 65 + e] * Sv[tok];
  }
}

extern "C" void kernel_launch(void* const* d_in, const int* in_sizes, int n_in,
                              void* d_out, int out_size, void* d_ws, size_t ws_size,
                              hipStream_t stream) {
  const float* x = (const float*)d_in[0];
  const float* W = (const float*)d_in[1];
  const int ntok = in_sizes[0] / IN_DIM_C;  // 65536

  float* out_idx = (float*)d_out;                    // [ntok,2]
  float* out_w   = out_idx + (size_t)ntok * 2;       // [ntok,2]
  float* out_p   = out_w + (size_t)ntok * 2;         // [ntok,64]

  const int blocks = ntok / MTILE;  // 512
  router_fused<<<blocks, 256, 0, stream>>>(x, W, out_idx, out_w, out_p);
}

// Round 2
// 768.642 us; speedup vs baseline: 1.0486x; 1.0486x over previous
//
#include <hip/hip_runtime.h>
#include <hip/hip_bf16.h>
#include <math.h>

typedef short s8v  __attribute__((ext_vector_type(8)));   // 8 bf16 (MFMA A/B frag)
typedef float f4v  __attribute__((ext_vector_type(4)));   // MFMA C/D frag
typedef unsigned short ushort_t;

constexpr int IN_DIM_C = 2048;
constexpr int NEXP     = 64;
constexpr int MTILE    = 128;               // tokens per block: 4 waves x 32
constexpr int KC       = 32;                // K per MFMA chunk
constexpr int NCHUNK   = IN_DIM_C / KC;     // 64

// Round-to-nearest-even fp32 -> bf16 hi, then bf16(residual) -> lo.
// x ~= hi + lo with |dropped lo*lo product| ~ 2^-18 |x||w|.
__device__ __forceinline__ void split_bf16(float f, ushort_t& hi, ushort_t& lo) {
  unsigned u = __float_as_uint(f);
  unsigned r = u + 0x7FFFu + ((u >> 16) & 1u);
  hi = (ushort_t)(r >> 16);
  float hif = __uint_as_float(r & 0xFFFF0000u);   // exact bf16 value of hi
  float lof = f - hif;                             // exact residual in fp32
  unsigned ul = __float_as_uint(lof);
  unsigned rl = ul + 0x7FFFu + ((ul >> 16) & 1u);
  lo = (ushort_t)(rl >> 16);
}

// Pre-kernel: split W [64,2048] fp32 into bf16 hi/lo planes in d_ws (512 KB).
__global__ void conv_w_kernel(const float* __restrict__ W,
                              ushort_t* __restrict__ w_hi, ushort_t* __restrict__ w_lo) {
  const int i = blockIdx.x * 256 + threadIdx.x;   // grid covers 131072 exactly
  ushort_t h, l;
  split_bf16(W[i], h, l);
  w_hi[i] = h;
  w_lo[i] = l;
}

// Main fused kernel. Wave-tile: 32 tokens x 64 experts = 2 M-tiles x 4 N-tiles of
// 16x16x32 bf16 MFMA, 3 products (hh, hl, lh) per tile. No LDS in the K-loop:
// A frags load direct from global (16 rows x 128B fully-consumed lines), B frags
// are preconverted bf16 from d_ws (L2-resident). Register-double-buffered chunks.
__global__ __launch_bounds__(256, 2)
void router_mfma(const float* __restrict__ x,
                 const ushort_t* __restrict__ w_hi, const ushort_t* __restrict__ w_lo,
                 float* __restrict__ out_idx, float* __restrict__ out_w,
                 float* __restrict__ out_p) {
  __shared__ float L[MTILE * 65 + MTILE];   // logits tile (stride 65) + per-token 1/sum
  float* Sv = L + MTILE * 65;

  const int tid   = threadIdx.x;
  const int lane  = tid & 63;
  const int wave  = tid >> 6;        // 0..3
  const int row16 = lane & 15;       // M/N index within a 16-tile
  const int quad  = lane >> 4;       // 0..3, k-octet selector
  const int m0    = blockIdx.x * MTILE;

  // A: lane reads 8 contiguous fp32 of its token row at k = quad*8 (+chunk)
  const float* a0 = x + (size_t)(m0 + wave * 32 + row16) * IN_DIM_C + quad * 8;
  const float* a1 = a0 + (size_t)16 * IN_DIM_C;
  // B: lane reads 8 contiguous bf16 of expert row (nt*16 + row16) at k = quad*8
  const size_t boff = (size_t)row16 * IN_DIM_C + quad * 8;

  f4v acc[2][4];
#pragma unroll
  for (int mt = 0; mt < 2; ++mt)
#pragma unroll
    for (int nt = 0; nt < 4; ++nt) acc[mt][nt] = (f4v){0.f, 0.f, 0.f, 0.f};

  float4 ar[2][2], an[2][2];
  s8v bh[4], bl[4], bnh[4], bnl[4];

  // Prologue: chunk 0
#pragma unroll
  for (int mt = 0; mt < 2; ++mt) {
    const float* ap = mt ? a1 : a0;
    ar[mt][0] = *(const float4*)(ap + 0);
    ar[mt][1] = *(const float4*)(ap + 4);
  }
#pragma unroll
  for (int nt = 0; nt < 4; ++nt) {
    bh[nt] = *(const s8v*)(w_hi + boff + (size_t)nt * 16 * IN_DIM_C);
    bl[nt] = *(const s8v*)(w_lo + boff + (size_t)nt * 16 * IN_DIM_C);
  }

  for (int c = 0; c < NCHUNK; ++c) {
    // Prefetch next chunk (registers only; wave-uniform predicate)
    if (c + 1 < NCHUNK) {
      const int kn = (c + 1) * KC;
#pragma unroll
      for (int mt = 0; mt < 2; ++mt) {
        const float* ap = (mt ? a1 : a0) + kn;
        an[mt][0] = *(const float4*)(ap + 0);
        an[mt][1] = *(const float4*)(ap + 4);
      }
#pragma unroll
      for (int nt = 0; nt < 4; ++nt) {
        bnh[nt] = *(const s8v*)(w_hi + boff + (size_t)nt * 16 * IN_DIM_C + kn);
        bnl[nt] = *(const s8v*)(w_lo + boff + (size_t)nt * 16 * IN_DIM_C + kn);
      }
    }

    // Convert current A chunk to hi/lo bf16 frags
    s8v ah[2], al[2];
#pragma unroll
    for (int mt = 0; mt < 2; ++mt) {
      const float xv[8] = {ar[mt][0].x, ar[mt][0].y, ar[mt][0].z, ar[mt][0].w,
                           ar[mt][1].x, ar[mt][1].y, ar[mt][1].z, ar[mt][1].w};
#pragma unroll
      for (int j = 0; j < 8; ++j) {
        ushort_t h, l;
        split_bf16(xv[j], h, l);
        ah[mt][j] = (short)h;
        al[mt][j] = (short)l;
      }
    }

    // 24 MFMAs: hh + hl + lh for each of the 8 (mt,nt) tiles
#pragma unroll
    for (int nt = 0; nt < 4; ++nt)
#pragma unroll
      for (int mt = 0; mt < 2; ++mt) {
        acc[mt][nt] = __builtin_amdgcn_mfma_f32_16x16x32_bf16(ah[mt], bh[nt], acc[mt][nt], 0, 0, 0);
        acc[mt][nt] = __builtin_amdgcn_mfma_f32_16x16x32_bf16(ah[mt], bl[nt], acc[mt][nt], 0, 0, 0);
        acc[mt][nt] = __builtin_amdgcn_mfma_f32_16x16x32_bf16(al[mt], bh[nt], acc[mt][nt], 0, 0, 0);
      }

    // Rotate register buffers
#pragma unroll
    for (int mt = 0; mt < 2; ++mt) { ar[mt][0] = an[mt][0]; ar[mt][1] = an[mt][1]; }
#pragma unroll
    for (int nt = 0; nt < 4; ++nt) { bh[nt] = bnh[nt]; bl[nt] = bnl[nt]; }
  }

  // Epilogue: scatter logits to LDS. C/D layout: col(expert)=lane&15, row(token)=quad*4+reg.
#pragma unroll
  for (int mt = 0; mt < 2; ++mt)
#pragma unroll
    for (int nt = 0; nt < 4; ++nt)
#pragma unroll
      for (int r = 0; r < 4; ++r) {
        const int tok = wave * 32 + mt * 16 + quad * 4 + r;
        const int e   = nt * 16 + row16;
        L[tok * 65 + e] = acc[mt][nt][r];
      }
  __syncthreads();

  if (tid < MTILE) {
    const int tok = tid;
    // Top-2 on raw logits (ties keep lower index, matching lax.top_k)
    float v1 = -1e30f, v2 = -1e30f;
    int i1 = 0, i2 = 0;
    for (int e = 0; e < NEXP; ++e) {
      const float l = L[tok * 65 + e];
      if (l > v1) { v2 = v1; i2 = i1; v1 = l; i1 = e; }
      else if (l > v2) { v2 = l; i2 = e; }
    }
    float S = 0.f;
    for (int e = 0; e < NEXP; ++e) {
      const float ex = __expf(L[tok * 65 + e] - v1);
      L[tok * 65 + e] = ex;
      S += ex;
    }
    Sv[tok] = 1.f / S;

    const float e2  = __expf(v2 - v1);
    const float inv = 1.f / (1.f + e2);
    const size_t g = (size_t)(m0 + tok);
    out_idx[g * 2 + 0] = (float)i1;
    out_idx[g * 2 + 1] = (float)i2;
    out_w[g * 2 + 0]   = inv;
    out_w[g * 2 + 1]   = e2 * inv;
  }
  __syncthreads();

  // Coalesced probs write
  const size_t pbase = (size_t)m0 * NEXP;
#pragma unroll
  for (int r = 0; r < (MTILE * NEXP) / 256; ++r) {
    const int idx = r * 256 + tid;
    const int tok = idx >> 6, e = idx & 63;
    out_p[pbase + idx] = L[tok * 65 + e] * Sv[tok];
  }
}

extern "C" void kernel_launch(void* const* d_in, const int* in_sizes, int n_in,
                              void* d_out, int out_size, void* d_ws, size_t ws_size,
                              hipStream_t stream) {
  const float* x = (const float*)d_in[0];
  const float* W = (const float*)d_in[1];
  const int ntok = in_sizes[0] / IN_DIM_C;   // 65536

  float* out_idx = (float*)d_out;                 // [ntok,2]
  float* out_w   = out_idx + (size_t)ntok * 2;    // [ntok,2]
  float* out_p   = out_w + (size_t)ntok * 2;      // [ntok,64]

  // d_ws: W bf16 hi/lo planes, 2 * 131072 ushort = 512 KB
  ushort_t* w_hi = (ushort_t*)d_ws;
  ushort_t* w_lo = w_hi + (size_t)NEXP * IN_DIM_C;

  conv_w_kernel<<<(NEXP * IN_DIM_C) / 256, 256, 0, stream>>>(W, w_hi, w_lo);

  const int blocks = ntok / MTILE;   // 512
  router_mfma<<<blocks, 256, 0, stream>>>(x, w_hi, w_lo, out_idx, out_w, out_p);
}